// Round 2
// baseline (1779.336 us; speedup 1.0000x reference)
//
#include <hip/hip_runtime.h>

constexpr int NN   = 100000;
constexpr int NE   = 3200000;
constexpr int FIN  = 512;
constexpr int FH   = 16;
constexpr int FOUT = 64;

__global__ void k_init_deg(float* __restrict__ deg) {
    int i = blockIdx.x * 256 + threadIdx.x;
    if (i < NN) deg[i] = 1.0f;   // self-loop contributes 1
}

__global__ void k_count_deg(const int* __restrict__ ei, float* __restrict__ deg) {
    int e = blockIdx.x * 256 + threadIdx.x;
    if (e < NE) atomicAdd(&deg[ei[NE + e]], 1.0f);
}

__global__ void k_rsqrt(float* __restrict__ deg) {
    int i = blockIdx.x * 256 + threadIdx.x;
    if (i < NN) deg[i] = rsqrtf(deg[i]);   // deg >= 1 always
}

// xw = x @ W1   [NN,512] x [512,16] -> [NN,16]
// 64 nodes/block, k-chunks of 128. W1 chunk (128x16=8KB) + x tile 64x132 (33.8KB) in LDS.
__global__ __launch_bounds__(256) void k_gemm1(const float* __restrict__ x,
                                               const float* __restrict__ W1,
                                               float* __restrict__ xw) {
    __shared__ float ws[128 * FH];    // 8 KB, per-k-chunk
    __shared__ float xs[64 * 132];    // 33.8 KB, pad 128->132 (16B-aligned rows, 2-way max)
    int t = threadIdx.x;
    int row0 = blockIdx.x * 64;
    int r  = t >> 2;          // node within tile (0..63)
    int jb = (t & 3) * 4;     // output group of 4
    float acc0 = 0.f, acc1 = 0.f, acc2 = 0.f, acc3 = 0.f;

    for (int kc = 0; kc < 4; ++kc) {
        __syncthreads();
        // stage W1 chunk: 2048 floats = 512 float4, 2 per thread
        {
            const float* wsrc = &W1[kc * 128 * FH];
            *(float4*)&ws[t * 4]        = *(const float4*)&wsrc[t * 4];
            *(float4*)&ws[1024 + t * 4] = *(const float4*)&wsrc[1024 + t * 4];
        }
        // stage x tile: 64 rows x 128 cols
        for (int it = 0; it < 8; ++it) {
            int idx = it * 1024 + t * 4;      // 0..8191
            int rr = idx >> 7;
            int cc = idx & 127;
            int gr = row0 + rr; if (gr >= NN) gr = NN - 1;
            *(float4*)&xs[rr * 132 + cc] = *(const float4*)&x[(size_t)gr * FIN + kc * 128 + cc];
        }
        __syncthreads();
        const float* xrow = &xs[r * 132];
        #pragma unroll 8
        for (int k = 0; k < 128; ++k) {
            float xv = xrow[k];
            float4 w = *(const float4*)&ws[k * FH + jb];
            acc0 += xv * w.x; acc1 += xv * w.y; acc2 += xv * w.z; acc3 += xv * w.w;
        }
    }
    int node = row0 + r;
    if (node < NN)
        *(float4*)&xw[node * FH + jb] = make_float4(acc0, acc1, acc2, acc3);
}

// agg[i][:] = dis[i]^2 * v[i][:]   (self-loop term; also serves as the zero-init)
__global__ void k_agg_init(const float* __restrict__ v, const float* __restrict__ dis,
                           float* __restrict__ agg) {
    int i = blockIdx.x * 256 + threadIdx.x;  // over NN*FH
    if (i < NN * FH) {
        float dv = dis[i >> 4];
        agg[i] = dv * dv * v[i];
    }
}

// scatter-add: 4 threads per edge, each handles 4 features (float4 gather + 4 atomics)
__global__ void k_agg_edges(const int* __restrict__ ei, const float* __restrict__ dis,
                            const float* __restrict__ v, float* __restrict__ agg) {
    int t = blockIdx.x * 256 + threadIdx.x;
    int e = t >> 2;
    int q = t & 3;
    if (e < NE) {
        int s = ei[e];
        int d = ei[NE + e];
        float nrm = dis[s] * dis[d];
        float4 val = *(const float4*)&v[s * FH + q * 4];
        float* ap = &agg[d * FH + q * 4];
        atomicAdd(ap + 0, nrm * val.x);
        atomicAdd(ap + 1, nrm * val.y);
        atomicAdd(ap + 2, nrm * val.z);
        atomicAdd(ap + 3, nrm * val.w);
    }
}

// in-place capable: h[i] = relu(agg[i] + b[i&15])
__global__ void k_relu_bias(const float* __restrict__ agg, const float* __restrict__ b,
                            float* __restrict__ h) {
    int i = blockIdx.x * 256 + threadIdx.x;
    if (i < NN * FH) {
        float vv = agg[i] + b[i & 15];
        h[i] = vv > 0.f ? vv : 0.f;
    }
}

// out = relu(agg2 @ W2 + b2)   [NN,16] x [16,64] -> [NN,64]; one wave per node
__global__ __launch_bounds__(256) void k_gemm2(const float* __restrict__ agg2,
                                               const float* __restrict__ W2,
                                               const float* __restrict__ b2,
                                               float* __restrict__ out) {
    __shared__ float ws[FH * FOUT];   // 4 KB
    int t = threadIdx.x;
    *(float4*)&ws[t * 4] = *(const float4*)&W2[t * 4];   // 256 threads x 4 = 1024 exactly
    __syncthreads();
    int wave = t >> 6, lane = t & 63;
    int node = blockIdx.x * 4 + wave;
    if (node >= NN) return;
    float vv = (lane < FH) ? agg2[node * FH + lane] : 0.0f;
    float acc = 0.0f;
    #pragma unroll
    for (int k = 0; k < FH; ++k) {
        float xk = __shfl(vv, k, 64);
        acc += xk * ws[k * FOUT + lane];
    }
    acc += b2[lane];
    out[node * FOUT + lane] = acc > 0.f ? acc : 0.f;
}

extern "C" void kernel_launch(void* const* d_in, const int* in_sizes, int n_in,
                              void* d_out, int out_size, void* d_ws, size_t ws_size,
                              hipStream_t stream) {
    const float* x  = (const float*)d_in[0];
    const int*   ei = (const int*)d_in[1];     // harness delivers integer inputs as int32
    const float* W1 = (const float*)d_in[2];
    const float* b1 = (const float*)d_in[3];
    const float* W2 = (const float*)d_in[4];
    const float* b2 = (const float*)d_in[5];
    float* out = (float*)d_out;

    // workspace: dis [NN] + two ping-pong buffers [NN*16] each = 13.2 MB
    float* ws_f = (float*)d_ws;
    float* dis  = ws_f;                    // NN (padded to 100032 for alignment)
    float* buf1 = ws_f + 100032;           // xw, later agg2
    float* buf2 = buf1 + NN * FH;          // agg1, later h (in-place relu)

    k_init_deg <<<(NN + 255) / 256, 256, 0, stream>>>(dis);
    k_count_deg<<<(NE + 255) / 256, 256, 0, stream>>>(ei, dis);
    k_rsqrt    <<<(NN + 255) / 256, 256, 0, stream>>>(dis);

    // layer 1: xw = x@W1 -> buf1
    k_gemm1    <<<(NN + 63) / 64, 256, 0, stream>>>(x, W1, buf1);
    // agg1 -> buf2
    k_agg_init <<<(NN * FH + 255) / 256, 256, 0, stream>>>(buf1, dis, buf2);
    k_agg_edges<<<(NE * 4 + 255) / 256, 256, 0, stream>>>(ei, dis, buf1, buf2);
    // h = relu(agg1+b1) in-place in buf2
    k_relu_bias<<<(NN * FH + 255) / 256, 256, 0, stream>>>(buf2, b1, buf2);

    // layer 2: aggregate h first (16 wide), then GEMM with W2
    // agg2 -> buf1 (xw dead now)
    k_agg_init <<<(NN * FH + 255) / 256, 256, 0, stream>>>(buf2, dis, buf1);
    k_agg_edges<<<(NE * 4 + 255) / 256, 256, 0, stream>>>(ei, dis, buf2, buf1);

    k_gemm2    <<<(NN + 3) / 4, 256, 0, stream>>>(buf1, W2, b2, out);
}

// Round 3
// 1115.258 us; speedup vs baseline: 1.5954x; 1.5954x over previous
//
#include <hip/hip_runtime.h>

constexpr int NN   = 100000;
constexpr int NE   = 3200000;
constexpr int FIN  = 512;
constexpr int FH   = 16;
constexpr int FOUT = 64;

__global__ void k_zero(int* __restrict__ p, int n) {
    int i = blockIdx.x * 256 + threadIdx.x;
    if (i < n) p[i] = 0;
}

// in-degree histogram over dst
__global__ void k_hist(const int* __restrict__ ei, int* __restrict__ cnt) {
    int e = blockIdx.x * 256 + threadIdx.x;
    if (e < NE) atomicAdd(&cnt[ei[NE + e]], 1);
}

__global__ void k_dis(const int* __restrict__ cnt, float* __restrict__ dis) {
    int i = blockIdx.x * 256 + threadIdx.x;
    if (i < NN) dis[i] = rsqrtf((float)cnt[i] + 1.0f);   // +1 self-loop
}

// single-block exclusive scan of cnt -> rowptr (and cursor copy).
// 1024 threads x 98 contiguous elements each (1024*98 = 100352 >= NN).
__global__ __launch_bounds__(1024) void k_scan(const int* __restrict__ cnt,
                                               int* __restrict__ rowptr,
                                               int* __restrict__ cursor) {
    __shared__ int wsum[16];
    int t = threadIdx.x;
    const int C = 98;
    int beg = t * C;
    int end = beg + C; if (end > NN) end = NN;
    int s = 0;
    for (int i = beg; i < end; ++i) s += cnt[i];
    int lane = t & 63, wid = t >> 6;
    int v = s;
    #pragma unroll
    for (int off = 1; off < 64; off <<= 1) {
        int u = __shfl_up(v, off, 64);
        if (lane >= off) v += u;
    }
    if (lane == 63) wsum[wid] = v;
    __syncthreads();
    if (wid == 0 && lane < 16) {
        int w = wsum[lane];
        #pragma unroll
        for (int off = 1; off < 16; off <<= 1) {
            int u = __shfl_up(w, off, 64);
            if (lane >= off) w += u;
        }
        wsum[lane] = w;
    }
    __syncthreads();
    int p = ((wid > 0) ? wsum[wid - 1] : 0) + (v - s);   // exclusive prefix
    for (int i = beg; i < end; ++i) {
        rowptr[i] = p; cursor[i] = p; p += cnt[i];
    }
}

// bucket edges by destination: sorted_src[rowptr[d]..] = all srcs pointing at d
__global__ void k_scatter(const int* __restrict__ ei, int* __restrict__ cursor,
                          int* __restrict__ ssrc) {
    int e = blockIdx.x * 256 + threadIdx.x;
    if (e < NE) {
        int s = ei[e];
        int d = ei[NE + e];
        int pos = atomicAdd(&cursor[d], 1);
        ssrc[pos] = s;
    }
}

// vp1 = dis * (x @ W1)   [NN,512]x[512,16] -> [NN,16]
// 64 nodes/block, k-chunks of 128. W1 chunk 8KB + x tile 64x132 (33.8KB) in LDS.
__global__ __launch_bounds__(256) void k_gemm1(const float* __restrict__ x,
                                               const float* __restrict__ W1,
                                               const float* __restrict__ dis,
                                               float* __restrict__ vp1) {
    __shared__ float ws[128 * FH];
    __shared__ float xs[64 * 132];
    int t = threadIdx.x;
    int row0 = blockIdx.x * 64;
    int r  = t >> 2;
    int jb = (t & 3) * 4;
    float acc0 = 0.f, acc1 = 0.f, acc2 = 0.f, acc3 = 0.f;

    for (int kc = 0; kc < 4; ++kc) {
        __syncthreads();
        {
            const float* wsrc = &W1[kc * 128 * FH];
            *(float4*)&ws[t * 4]        = *(const float4*)&wsrc[t * 4];
            *(float4*)&ws[1024 + t * 4] = *(const float4*)&wsrc[1024 + t * 4];
        }
        for (int it = 0; it < 8; ++it) {
            int idx = it * 1024 + t * 4;
            int rr = idx >> 7;
            int cc = idx & 127;
            int gr = row0 + rr; if (gr >= NN) gr = NN - 1;
            *(float4*)&xs[rr * 132 + cc] = *(const float4*)&x[(size_t)gr * FIN + kc * 128 + cc];
        }
        __syncthreads();
        const float* xrow = &xs[r * 132];
        #pragma unroll 8
        for (int k = 0; k < 128; ++k) {
            float xv = xrow[k];
            float4 w = *(const float4*)&ws[k * FH + jb];
            acc0 += xv * w.x; acc1 += xv * w.y; acc2 += xv * w.z; acc3 += xv * w.w;
        }
    }
    int node = row0 + r;
    if (node < NN) {
        float d = dis[node];
        *(float4*)&vp1[node * FH + jb] = make_float4(d*acc0, d*acc1, d*acc2, d*acc3);
    }
}

// layer-1 aggregate + bias + relu + pre-scale for layer 2:
// vp2[d] = dis[d] * relu(dis[d]*(vp1[d] + sum_{s in N(d)} vp1[s]) + b1)
// 16 lanes per node, 16 nodes per 256-block. rowend = cursor after scatter.
__global__ __launch_bounds__(256) void k_agg1(const int* __restrict__ rowptr,
                                              const int* __restrict__ rowend,
                                              const int* __restrict__ ssrc,
                                              const float* __restrict__ dis,
                                              const float* __restrict__ vp1,
                                              const float* __restrict__ b1,
                                              float* __restrict__ vp2) {
    int t = threadIdx.x;
    int node = blockIdx.x * 16 + (t >> 4);
    int lane = t & 15;
    float sum = vp1[node * FH + lane];
    int e0 = rowptr[node], e1 = rowend[node];
    int e = e0;
    int sn = (e < e1) ? ssrc[e] : 0;
    while (e < e1) {
        int s = sn;
        ++e;
        sn = (e < e1) ? ssrc[e] : 0;
        sum += vp1[s * FH + lane];
    }
    float d = dis[node];
    float h = d * sum + b1[lane];
    h = h > 0.f ? h : 0.f;
    vp2[node * FH + lane] = d * h;
}

// layer-2 aggregate fused with GEMM2 + bias + relu:
// a16 = dis[d]*(vp2[d] + sum vp2[s]);  out[d] = relu(a16 @ W2 + b2)
__global__ __launch_bounds__(256) void k_agg2_gemm2(const int* __restrict__ rowptr,
                                                    const int* __restrict__ rowend,
                                                    const int* __restrict__ ssrc,
                                                    const float* __restrict__ dis,
                                                    const float* __restrict__ vp2,
                                                    const float* __restrict__ W2,
                                                    const float* __restrict__ b2,
                                                    float* __restrict__ out) {
    __shared__ float ws[FH * FOUT];   // 4 KB
    int t = threadIdx.x;
    *(float4*)&ws[t * 4] = *(const float4*)&W2[t * 4];
    __syncthreads();
    int node = blockIdx.x * 16 + (t >> 4);   // grid sized so node < NN always
    int lane = t & 15;
    int wl = t & 63;
    float sum = vp2[node * FH + lane];
    int e0 = rowptr[node], e1 = rowend[node];
    int e = e0;
    int sn = (e < e1) ? ssrc[e] : 0;
    while (e < e1) {
        int s = sn;
        ++e;
        sn = (e < e1) ? ssrc[e] : 0;
        sum += vp2[s * FH + lane];
    }
    sum *= dis[node];   // agg2[node][lane]
    // 16 lanes -> 64 outputs; each lane computes 4 consecutive outputs
    float4 acc = make_float4(0.f, 0.f, 0.f, 0.f);
    int qb = wl & 48;
    #pragma unroll
    for (int k = 0; k < FH; ++k) {
        float ak = __shfl(sum, qb + k, 64);
        float4 w = *(const float4*)&ws[k * FOUT + lane * 4];
        acc.x += ak * w.x; acc.y += ak * w.y; acc.z += ak * w.z; acc.w += ak * w.w;
    }
    float4 bb = *(const float4*)&b2[lane * 4];
    float4 r;
    r.x = fmaxf(acc.x + bb.x, 0.f);
    r.y = fmaxf(acc.y + bb.y, 0.f);
    r.z = fmaxf(acc.z + bb.z, 0.f);
    r.w = fmaxf(acc.w + bb.w, 0.f);
    *(float4*)&out[node * FOUT + lane * 4] = r;
}

extern "C" void kernel_launch(void* const* d_in, const int* in_sizes, int n_in,
                              void* d_out, int out_size, void* d_ws, size_t ws_size,
                              hipStream_t stream) {
    const float* x  = (const float*)d_in[0];
    const int*   ei = (const int*)d_in[1];
    const float* W1 = (const float*)d_in[2];
    const float* b1 = (const float*)d_in[3];
    const float* W2 = (const float*)d_in[4];
    const float* b2 = (const float*)d_in[5];
    float* out = (float*)d_out;

    // workspace layout (27.2 MB total)
    char* p = (char*)d_ws;
    int*   cnt    = (int*)p;              p += 100032 * 4;
    int*   rowptr = (int*)p;              p += 100032 * 4;
    int*   cursor = (int*)p;              p += 100032 * 4;
    float* dis    = (float*)p;            p += 100032 * 4;
    int*   ssrc   = (int*)p;              p += (size_t)NE * 4;
    float* vp1    = (float*)p;            p += (size_t)NN * FH * 4;
    float* vp2    = (float*)p;

    // CSR build
    k_zero   <<<(NN + 255) / 256, 256, 0, stream>>>(cnt, NN);
    k_hist   <<<(NE + 255) / 256, 256, 0, stream>>>(ei, cnt);
    k_dis    <<<(NN + 255) / 256, 256, 0, stream>>>(cnt, dis);
    k_scan   <<<1, 1024, 0, stream>>>(cnt, rowptr, cursor);
    k_scatter<<<(NE + 255) / 256, 256, 0, stream>>>(ei, cursor, ssrc);
    // after scatter: cursor[d] == rowptr[d+1]

    // layer 1
    k_gemm1  <<<(NN + 63) / 64, 256, 0, stream>>>(x, W1, dis, vp1);
    k_agg1   <<<NN / 16, 256, 0, stream>>>(rowptr, cursor, ssrc, dis, vp1, b1, vp2);

    // layer 2 (agg + gemm2 fused)
    k_agg2_gemm2<<<NN / 16, 256, 0, stream>>>(rowptr, cursor, ssrc, dis, vp2, W2, b2, out);
}

// Round 4
// 1079.142 us; speedup vs baseline: 1.6488x; 1.0335x over previous
//
#include <hip/hip_runtime.h>

constexpr int NN   = 100000;
constexpr int NE   = 3200000;
constexpr int FIN  = 512;
constexpr int FH   = 16;
constexpr int FOUT = 64;

constexpr int BSH = 7;                     // bucket shift (128 nodes/bucket)
constexpr int BSZ = 128;
constexpr int K   = (NN + BSZ - 1) / BSZ;  // 782 buckets
constexpr int NB  = 512;                   // binning blocks
constexpr int CHUNK = NE / NB;             // 6250 edges per block (exact)

// per-block bucket counts: M[k*NB + b]
__global__ __launch_bounds__(256) void k_cnt(const int* __restrict__ ei, int* __restrict__ M) {
    __shared__ int h[K];
    int t = threadIdx.x, b = blockIdx.x;
    for (int i = t; i < K; i += 256) h[i] = 0;
    __syncthreads();
    int e0 = b * CHUNK;
    for (int e = e0 + t; e < e0 + CHUNK; e += 256)
        atomicAdd(&h[ei[NE + e] >> BSH], 1);
    __syncthreads();
    for (int i = t; i < K; i += 256) M[i * NB + b] = h[i];
}

// per bucket-row exclusive scan over the NB blocks, in place; bucket totals out.
__global__ __launch_bounds__(256) void k_scanM(int* __restrict__ M, int* __restrict__ btot) {
    int k = blockIdx.x, t = threadIdx.x;
    int2* row = (int2*)(M + (size_t)k * NB);
    int2 v = row[t];                       // 256 threads x 2 = NB
    int s = v.x + v.y;
    int lane = t & 63, wid = t >> 6;
    int ps = s;
    #pragma unroll
    for (int off = 1; off < 64; off <<= 1) {
        int u = __shfl_up(ps, off, 64);
        if (lane >= off) ps += u;
    }
    __shared__ int wsum[4];
    if (lane == 63) wsum[wid] = ps;
    __syncthreads();
    int base = 0;
    for (int w = 0; w < wid; ++w) base += wsum[w];
    int excl = base + ps - s;
    int2 o; o.x = excl; o.y = excl + v.x;
    row[t] = o;
    if (t == 255) btot[k] = excl + s;
}

// exclusive scan of bucket totals -> bstart[K+1]
__global__ __launch_bounds__(1024) void k_scanB(const int* __restrict__ btot, int* __restrict__ bstart) {
    int t = threadIdx.x;
    int v = (t < K) ? btot[t] : 0;
    int lane = t & 63, wid = t >> 6;
    int ps = v;
    #pragma unroll
    for (int off = 1; off < 64; off <<= 1) {
        int u = __shfl_up(ps, off, 64);
        if (lane >= off) ps += u;
    }
    __shared__ int wsum[16];
    if (lane == 63) wsum[wid] = ps;
    __syncthreads();
    int base = 0;
    for (int w = 0; w < wid; ++w) base += wsum[w];
    int excl = base + ps - v;
    if (t < K) bstart[t] = excl;
    if (t == 0) bstart[K] = NE;
}

// deterministic scatter: rec[pos] = (src<<7) | d_local, positions from scans (LDS cursors only)
__global__ __launch_bounds__(256) void k_scatter2(const int* __restrict__ ei,
                                                  const int* __restrict__ M,
                                                  const int* __restrict__ bstart,
                                                  int* __restrict__ rec) {
    __shared__ int cur[K];
    int t = threadIdx.x, b = blockIdx.x;
    for (int i = t; i < K; i += 256) cur[i] = bstart[i] + M[i * NB + b];
    __syncthreads();
    int e0 = b * CHUNK;
    for (int e = e0 + t; e < e0 + CHUNK; e += 256) {
        int s = ei[e];
        int d = ei[NE + e];
        int pos = atomicAdd(&cur[d >> BSH], 1);
        rec[pos] = (s << BSH) | (d & (BSZ - 1));
    }
}

// per-bucket degree histogram -> dis = rsqrt(deg+1)
__global__ __launch_bounds__(256) void k_deg_dis(const int* __restrict__ rec,
                                                 const int* __restrict__ bstart,
                                                 float* __restrict__ dis) {
    __shared__ int h[BSZ];
    int t = threadIdx.x, k = blockIdx.x;
    if (t < BSZ) h[t] = 0;
    __syncthreads();
    int e0 = bstart[k], e1 = bstart[k + 1];
    for (int e = e0 + t; e < e1; e += 256)
        atomicAdd(&h[rec[e] & (BSZ - 1)], 1);
    __syncthreads();
    if (t < BSZ) {
        int node = k * BSZ + t;
        if (node < NN) dis[node] = rsqrtf((float)h[t] + 1.0f);
    }
}

// vp1 = dis * (x @ W1)   [NN,512]x[512,16] -> [NN,16]
__global__ __launch_bounds__(256) void k_gemm1(const float* __restrict__ x,
                                               const float* __restrict__ W1,
                                               const float* __restrict__ dis,
                                               float* __restrict__ vp1) {
    __shared__ float ws[128 * FH];
    __shared__ float xs[64 * 132];
    int t = threadIdx.x;
    int row0 = blockIdx.x * 64;
    int r  = t >> 2;
    int jb = (t & 3) * 4;
    float acc0 = 0.f, acc1 = 0.f, acc2 = 0.f, acc3 = 0.f;

    for (int kc = 0; kc < 4; ++kc) {
        __syncthreads();
        {
            const float* wsrc = &W1[kc * 128 * FH];
            *(float4*)&ws[t * 4]        = *(const float4*)&wsrc[t * 4];
            *(float4*)&ws[1024 + t * 4] = *(const float4*)&wsrc[1024 + t * 4];
        }
        for (int it = 0; it < 8; ++it) {
            int idx = it * 1024 + t * 4;
            int rr = idx >> 7;
            int cc = idx & 127;
            int gr = row0 + rr; if (gr >= NN) gr = NN - 1;
            *(float4*)&xs[rr * 132 + cc] = *(const float4*)&x[(size_t)gr * FIN + kc * 128 + cc];
        }
        __syncthreads();
        const float* xrow = &xs[r * 132];
        #pragma unroll 8
        for (int k = 0; k < 128; ++k) {
            float xv = xrow[k];
            float4 w = *(const float4*)&ws[k * FH + jb];
            acc0 += xv * w.x; acc1 += xv * w.y; acc2 += xv * w.z; acc3 += xv * w.w;
        }
    }
    int node = row0 + r;
    if (node < NN) {
        float d = dis[node];
        *(float4*)&vp1[node * FH + jb] = make_float4(d*acc0, d*acc1, d*acc2, d*acc3);
    }
}

// layer-1 aggregate (LDS accumulator per bucket) + bias + relu + pre-scale:
// vp2[d] = dis[d] * relu(dis[d]*(vp1[d] + sum_s vp1[s]) + b1)
__global__ __launch_bounds__(256) void k_agg1(const int* __restrict__ rec,
                                              const int* __restrict__ bstart,
                                              const float* __restrict__ dis,
                                              const float* __restrict__ vp1,
                                              const float* __restrict__ b1,
                                              float* __restrict__ vp2) {
    __shared__ float acc[BSZ * FH];   // 8 KB
    int t = threadIdx.x, k = blockIdx.x;
    for (int i = t; i < BSZ * FH; i += 256) acc[i] = 0.f;
    __syncthreads();
    int e0 = bstart[k], e1 = bstart[k + 1];
    int es = t >> 4, f = t & 15;      // 16 edges in flight x 16 features
    for (int e = e0 + es; e < e1; e += 16) {
        int r = rec[e];
        float v = vp1[(r >> BSH) * FH + f];
        atomicAdd(&acc[(r & (BSZ - 1)) * FH + f], v);
    }
    __syncthreads();
    for (int i = t; i < BSZ * FH; i += 256) {
        int node = k * BSZ + (i >> 4);
        if (node < NN) {
            int ff = i & 15;
            float dv = dis[node];
            float h = dv * (acc[i] + vp1[node * FH + ff]) + b1[ff];
            h = h > 0.f ? h : 0.f;
            vp2[node * FH + ff] = dv * h;
        }
    }
}

// layer-2 aggregate + GEMM2(16->64) + bias + relu, all from LDS
__global__ __launch_bounds__(256) void k_agg2(const int* __restrict__ rec,
                                              const int* __restrict__ bstart,
                                              const float* __restrict__ dis,
                                              const float* __restrict__ vp2,
                                              const float* __restrict__ W2,
                                              const float* __restrict__ b2,
                                              float* __restrict__ out) {
    __shared__ float acc[BSZ * FH];   // 8 KB
    __shared__ float ws[FH * FOUT];   // 4 KB
    int t = threadIdx.x, k = blockIdx.x;
    *(float4*)&ws[t * 4] = *(const float4*)&W2[t * 4];
    for (int i = t; i < BSZ * FH; i += 256) acc[i] = 0.f;
    __syncthreads();
    int e0 = bstart[k], e1 = bstart[k + 1];
    int es = t >> 4, f = t & 15;
    for (int e = e0 + es; e < e1; e += 16) {
        int r = rec[e];
        float v = vp2[(r >> BSH) * FH + f];
        atomicAdd(&acc[(r & (BSZ - 1)) * FH + f], v);
    }
    __syncthreads();
    // finalize a16 in place: a16 = dis[d]*(acc + vp2[d])
    for (int i = t; i < BSZ * FH; i += 256) {
        int node = k * BSZ + (i >> 4);
        float dv = (node < NN) ? dis[node] : 0.f;
        float self = (node < NN) ? vp2[node * FH + (i & 15)] : 0.f;
        acc[i] = dv * (acc[i] + self);
    }
    __syncthreads();
    // GEMM: 4 nodes per pass x 64 output lanes
    int j = t & 63;
    float bj = b2[j];
    for (int n = t >> 6; n < BSZ; n += 4) {
        int node = k * BSZ + n;
        if (node >= NN) break;
        float s = 0.f;
        #pragma unroll
        for (int kk = 0; kk < FH; ++kk)
            s += acc[n * FH + kk] * ws[kk * FOUT + j];
        out[node * FOUT + j] = fmaxf(s + bj, 0.f);
    }
}

extern "C" void kernel_launch(void* const* d_in, const int* in_sizes, int n_in,
                              void* d_out, int out_size, void* d_ws, size_t ws_size,
                              hipStream_t stream) {
    const float* x  = (const float*)d_in[0];
    const int*   ei = (const int*)d_in[1];
    const float* W1 = (const float*)d_in[2];
    const float* b1 = (const float*)d_in[3];
    const float* W2 = (const float*)d_in[4];
    const float* b2 = (const float*)d_in[5];
    float* out = (float*)d_out;

    // workspace (~27.6 MB)
    char* p = (char*)d_ws;
    int*   M      = (int*)p;    p += (size_t)K * NB * 4;       // 1.6 MB
    int*   btot   = (int*)p;    p += 1024 * 4;
    int*   bstart = (int*)p;    p += 1024 * 4;
    int*   rec    = (int*)p;    p += (size_t)NE * 4;           // 12.8 MB
    float* dis    = (float*)p;  p += 100032 * 4;
    float* vp1    = (float*)p;  p += (size_t)NN * FH * 4;      // 6.4 MB
    float* vp2    = (float*)p;                                 // 6.4 MB

    k_cnt     <<<NB, 256, 0, stream>>>(ei, M);
    k_scanM   <<<K, 256, 0, stream>>>(M, btot);
    k_scanB   <<<1, 1024, 0, stream>>>(btot, bstart);
    k_scatter2<<<NB, 256, 0, stream>>>(ei, M, bstart, rec);
    k_deg_dis <<<K, 256, 0, stream>>>(rec, bstart, dis);

    k_gemm1   <<<(NN + 63) / 64, 256, 0, stream>>>(x, W1, dis, vp1);
    k_agg1    <<<K, 256, 0, stream>>>(rec, bstart, dis, vp1, b1, vp2);
    k_agg2    <<<K, 256, 0, stream>>>(rec, bstart, dis, vp2, W2, b2, out);
}

// Round 5
// 990.551 us; speedup vs baseline: 1.7963x; 1.0894x over previous
//
#include <hip/hip_runtime.h>

constexpr int NN   = 100000;
constexpr int NE   = 3200000;
constexpr int FIN  = 512;
constexpr int FH   = 16;
constexpr int FOUT = 64;

constexpr int BSH = 6;                     // bucket shift (64 nodes/bucket)
constexpr int BSZ = 64;
constexpr int K   = (NN + BSZ - 1) / BSZ;  // 1563 buckets
constexpr int NB  = 512;                   // binning blocks
constexpr int CHUNK = NE / NB;             // 6250 edges per block (exact)

// per-block bucket counts: M[k*NB + b]
__global__ __launch_bounds__(256) void k_cnt(const int* __restrict__ ei, int* __restrict__ M) {
    __shared__ int h[K];
    int t = threadIdx.x, b = blockIdx.x;
    for (int i = t; i < K; i += 256) h[i] = 0;
    __syncthreads();
    int e0 = b * CHUNK;
    for (int e = e0 + t; e < e0 + CHUNK; e += 256)
        atomicAdd(&h[ei[NE + e] >> BSH], 1);
    __syncthreads();
    for (int i = t; i < K; i += 256) M[i * NB + b] = h[i];
}

// per bucket-row exclusive scan over the NB blocks, in place; bucket totals out.
__global__ __launch_bounds__(256) void k_scanM(int* __restrict__ M, int* __restrict__ btot) {
    int k = blockIdx.x, t = threadIdx.x;
    int2* row = (int2*)(M + (size_t)k * NB);
    int2 v = row[t];                       // 256 threads x 2 = NB
    int s = v.x + v.y;
    int lane = t & 63, wid = t >> 6;
    int ps = s;
    #pragma unroll
    for (int off = 1; off < 64; off <<= 1) {
        int u = __shfl_up(ps, off, 64);
        if (lane >= off) ps += u;
    }
    __shared__ int wsum[4];
    if (lane == 63) wsum[wid] = ps;
    __syncthreads();
    int base = 0;
    for (int w = 0; w < wid; ++w) base += wsum[w];
    int excl = base + ps - s;
    int2 o; o.x = excl; o.y = excl + v.x;
    row[t] = o;
    if (t == 255) btot[k] = excl + s;
}

// exclusive scan of bucket totals (K=1563) -> bstart[K+1]; 2 elems/thread
__global__ __launch_bounds__(1024) void k_scanB(const int* __restrict__ btot, int* __restrict__ bstart) {
    int t = threadIdx.x;
    int i0 = 2 * t, i1 = 2 * t + 1;
    int c0 = (i0 < K) ? btot[i0] : 0;
    int c1 = (i1 < K) ? btot[i1] : 0;
    int s = c0 + c1;
    int lane = t & 63, wid = t >> 6;
    int ps = s;
    #pragma unroll
    for (int off = 1; off < 64; off <<= 1) {
        int u = __shfl_up(ps, off, 64);
        if (lane >= off) ps += u;
    }
    __shared__ int wsum[16];
    if (lane == 63) wsum[wid] = ps;
    __syncthreads();
    int base = 0;
    for (int w = 0; w < wid; ++w) base += wsum[w];
    int excl = base + ps - s;
    if (i0 < K) bstart[i0] = excl;
    if (i1 < K) bstart[i1] = excl + c0;
    if (t == 0) bstart[K] = NE;
}

// deterministic scatter: rec[pos] = (src<<6) | d_local, positions from scans (LDS cursors only)
__global__ __launch_bounds__(256) void k_scatter2(const int* __restrict__ ei,
                                                  const int* __restrict__ M,
                                                  const int* __restrict__ bstart,
                                                  int* __restrict__ rec) {
    __shared__ int cur[K];
    int t = threadIdx.x, b = blockIdx.x;
    for (int i = t; i < K; i += 256) cur[i] = bstart[i] + M[i * NB + b];
    __syncthreads();
    int e0 = b * CHUNK;
    for (int e = e0 + t; e < e0 + CHUNK; e += 256) {
        int s = ei[e];
        int d = ei[NE + e];
        int pos = atomicAdd(&cur[d >> BSH], 1);
        rec[pos] = (s << BSH) | (d & (BSZ - 1));
    }
}

// per-bucket degree histogram -> dis = rsqrt(deg+1)
__global__ __launch_bounds__(256) void k_deg_dis(const int* __restrict__ rec,
                                                 const int* __restrict__ bstart,
                                                 float* __restrict__ dis) {
    __shared__ int h[BSZ];
    int t = threadIdx.x, k = blockIdx.x;
    if (t < BSZ) h[t] = 0;
    __syncthreads();
    int e0 = bstart[k], e1 = bstart[k + 1];
    for (int e = e0 + t; e < e1; e += 256)
        atomicAdd(&h[rec[e] & (BSZ - 1)], 1);
    __syncthreads();
    if (t < BSZ) {
        int node = k * BSZ + t;
        if (node < NN) dis[node] = rsqrtf((float)h[t] + 1.0f);
    }
}

// vp1 = dis * (x @ W1)   [NN,512]x[512,16] -> [NN,16]
__global__ __launch_bounds__(256) void k_gemm1(const float* __restrict__ x,
                                               const float* __restrict__ W1,
                                               const float* __restrict__ dis,
                                               float* __restrict__ vp1) {
    __shared__ float ws[128 * FH];
    __shared__ float xs[64 * 132];
    int t = threadIdx.x;
    int row0 = blockIdx.x * 64;
    int r  = t >> 2;
    int jb = (t & 3) * 4;
    float acc0 = 0.f, acc1 = 0.f, acc2 = 0.f, acc3 = 0.f;

    for (int kc = 0; kc < 4; ++kc) {
        __syncthreads();
        {
            const float* wsrc = &W1[kc * 128 * FH];
            *(float4*)&ws[t * 4]        = *(const float4*)&wsrc[t * 4];
            *(float4*)&ws[1024 + t * 4] = *(const float4*)&wsrc[1024 + t * 4];
        }
        for (int it = 0; it < 8; ++it) {
            int idx = it * 1024 + t * 4;
            int rr = idx >> 7;
            int cc = idx & 127;
            int gr = row0 + rr; if (gr >= NN) gr = NN - 1;
            *(float4*)&xs[rr * 132 + cc] = *(const float4*)&x[(size_t)gr * FIN + kc * 128 + cc];
        }
        __syncthreads();
        const float* xrow = &xs[r * 132];
        #pragma unroll 8
        for (int k = 0; k < 128; ++k) {
            float xv = xrow[k];
            float4 w = *(const float4*)&ws[k * FH + jb];
            acc0 += xv * w.x; acc1 += xv * w.y; acc2 += xv * w.z; acc3 += xv * w.w;
        }
    }
    int node = row0 + r;
    if (node < NN) {
        float d = dis[node];
        *(float4*)&vp1[node * FH + jb] = make_float4(d*acc0, d*acc1, d*acc2, d*acc3);
    }
}

// edge-loop core: 4 lanes/edge, float4 gather, 2-way software pipeline.
// acc is LDS [BSZ*FH]; q = lane&3 selects the float4 quarter of the feature row.
__device__ __forceinline__ void agg_edges(const int* __restrict__ rec, int e0, int e1,
                                          const float* __restrict__ vp, float* acc,
                                          int slot, int q) {
    int e = e0 + slot;
    for (; e + BSZ < e1; e += 2 * BSZ) {
        int r0 = rec[e];
        int r1 = rec[e + BSZ];
        float4 v0 = *(const float4*)&vp[(r0 >> BSH) * FH + q * 4];
        float4 v1 = *(const float4*)&vp[(r1 >> BSH) * FH + q * 4];
        float* a0 = &acc[(r0 & (BSZ - 1)) * FH + q * 4];
        float* a1 = &acc[(r1 & (BSZ - 1)) * FH + q * 4];
        atomicAdd(a0 + 0, v0.x); atomicAdd(a0 + 1, v0.y);
        atomicAdd(a0 + 2, v0.z); atomicAdd(a0 + 3, v0.w);
        atomicAdd(a1 + 0, v1.x); atomicAdd(a1 + 1, v1.y);
        atomicAdd(a1 + 2, v1.z); atomicAdd(a1 + 3, v1.w);
    }
    if (e < e1) {
        int r0 = rec[e];
        float4 v0 = *(const float4*)&vp[(r0 >> BSH) * FH + q * 4];
        float* a0 = &acc[(r0 & (BSZ - 1)) * FH + q * 4];
        atomicAdd(a0 + 0, v0.x); atomicAdd(a0 + 1, v0.y);
        atomicAdd(a0 + 2, v0.z); atomicAdd(a0 + 3, v0.w);
    }
}

// layer-1 aggregate + bias + relu + pre-scale:
// vp2[d] = dis[d] * relu(dis[d]*(vp1[d] + sum_s vp1[s]) + b1)
__global__ __launch_bounds__(256) void k_agg1(const int* __restrict__ rec,
                                              const int* __restrict__ bstart,
                                              const float* __restrict__ dis,
                                              const float* __restrict__ vp1,
                                              const float* __restrict__ b1,
                                              float* __restrict__ vp2) {
    __shared__ float acc[BSZ * FH];   // 4 KB
    int t = threadIdx.x, k = blockIdx.x;
    for (int i = t; i < BSZ * FH; i += 256) acc[i] = 0.f;
    __syncthreads();
    agg_edges(rec, bstart[k], bstart[k + 1], vp1, acc, t >> 2, t & 3);
    __syncthreads();
    for (int i = t; i < BSZ * FH; i += 256) {
        int node = k * BSZ + (i >> 4);
        if (node < NN) {
            int ff = i & 15;
            float dv = dis[node];
            float h = dv * (acc[i] + vp1[node * FH + ff]) + b1[ff];
            h = h > 0.f ? h : 0.f;
            vp2[node * FH + ff] = dv * h;
        }
    }
}

// layer-2 aggregate + GEMM2(16->64) + bias + relu
__global__ __launch_bounds__(256) void k_agg2(const int* __restrict__ rec,
                                              const int* __restrict__ bstart,
                                              const float* __restrict__ dis,
                                              const float* __restrict__ vp2,
                                              const float* __restrict__ W2,
                                              const float* __restrict__ b2,
                                              float* __restrict__ out) {
    __shared__ float acc[BSZ * FH];   // 4 KB
    __shared__ float ws[FH * FOUT];   // 4 KB
    int t = threadIdx.x, k = blockIdx.x;
    *(float4*)&ws[t * 4] = *(const float4*)&W2[t * 4];
    for (int i = t; i < BSZ * FH; i += 256) acc[i] = 0.f;
    __syncthreads();
    agg_edges(rec, bstart[k], bstart[k + 1], vp2, acc, t >> 2, t & 3);
    __syncthreads();
    // finalize a16 in place: a16 = dis[d]*(acc + vp2[d])
    for (int i = t; i < BSZ * FH; i += 256) {
        int node = k * BSZ + (i >> 4);
        float dv = (node < NN) ? dis[node] : 0.f;
        float self = (node < NN) ? vp2[node * FH + (i & 15)] : 0.f;
        acc[i] = dv * (acc[i] + self);
    }
    __syncthreads();
    // GEMM: 4 nodes per pass x 64 output lanes
    int j = t & 63;
    float bj = b2[j];
    for (int n = t >> 6; n < BSZ; n += 4) {
        int node = k * BSZ + n;
        if (node >= NN) break;
        float s = 0.f;
        #pragma unroll
        for (int kk = 0; kk < FH; ++kk)
            s += acc[n * FH + kk] * ws[kk * FOUT + j];
        out[node * FOUT + j] = fmaxf(s + bj, 0.f);
    }
}

extern "C" void kernel_launch(void* const* d_in, const int* in_sizes, int n_in,
                              void* d_out, int out_size, void* d_ws, size_t ws_size,
                              hipStream_t stream) {
    const float* x  = (const float*)d_in[0];
    const int*   ei = (const int*)d_in[1];
    const float* W1 = (const float*)d_in[2];
    const float* b1 = (const float*)d_in[3];
    const float* W2 = (const float*)d_in[4];
    const float* b2 = (const float*)d_in[5];
    float* out = (float*)d_out;

    // workspace (~30 MB)
    char* p = (char*)d_ws;
    int*   M      = (int*)p;    p += (size_t)K * NB * 4;       // 3.2 MB
    int*   btot   = (int*)p;    p += 2048 * 4;
    int*   bstart = (int*)p;    p += 2048 * 4;
    int*   rec    = (int*)p;    p += (size_t)NE * 4;           // 12.8 MB
    float* dis    = (float*)p;  p += 100032 * 4;
    float* vp1    = (float*)p;  p += (size_t)NN * FH * 4;      // 6.4 MB
    float* vp2    = (float*)p;                                 // 6.4 MB

    k_cnt     <<<NB, 256, 0, stream>>>(ei, M);
    k_scanM   <<<K, 256, 0, stream>>>(M, btot);
    k_scanB   <<<1, 1024, 0, stream>>>(btot, bstart);
    k_scatter2<<<NB, 256, 0, stream>>>(ei, M, bstart, rec);
    k_deg_dis <<<K, 256, 0, stream>>>(rec, bstart, dis);

    k_gemm1   <<<(NN + 63) / 64, 256, 0, stream>>>(x, W1, dis, vp1);
    k_agg1    <<<K, 256, 0, stream>>>(rec, bstart, dis, vp1, b1, vp2);
    k_agg2    <<<K, 256, 0, stream>>>(rec, bstart, dis, vp2, W2, b2, out);
}